// Round 10
// baseline (154.676 us; speedup 1.0000x reference)
//
#include <hip/hip_runtime.h>

// GNN_17575006175684: 3-layer GCN + mean-pool + linear head + log_softmax.
// R10 = R9 with the CSR front-end collapsed to ONE edge pass:
//  - scatter_direct: per-chunk LDS histogram -> chunk-level reservation
//    (atomicAdd(&cur[bucket], chunkCount), 256 atomics/chunk not per-edge)
//    -> scatter into fixed-capacity buckets (CMAX=8192 vs mean 6250, +24sigma).
//    Overflow (essentially impossible, but handled for ANY input) spills to an
//    E-capacity list that group_csr drains -> unconditionally correct.
//    Replaces hist1+seg_scan+bucket_scan+scatter1 (edge stream now read once).
//  - groupBeg scan folded into group_csr (256-entry LDS scan per block).
//  - gather unroll 8 (latency-bound), dinv staged in LDS for phase B.
// Still: packed 4B edges, fused prescale, fused gather+matmul (bf16 tables,
// fp32 accum), atomic-free pool+head. 8 dispatches total.

#define BLK 256
#define CH 4096             // edges per chunk
#define EPT (CH / BLK)      // 16
#define NB 256              // buckets = dst>>9 (512 nodes each)
#define GSH 9
#define GSZ 512
#define CMAX 8192           // bucket slot capacity (mean 6250)

// ---------------- bf16 helpers (storage only) ----------------

__device__ inline float bfu_lo(unsigned int w) { return __uint_as_float(w << 16); }
__device__ inline float bfu_hi(unsigned int w) { return __uint_as_float(w & 0xffff0000u); }
__device__ inline unsigned int f2bf(float f) {   // RNE
    unsigned int w = __float_as_uint(f);
    return (w + 0x7fffu + ((w >> 16) & 1u)) >> 16;
}
__device__ inline unsigned int pack2(float a, float b) {
    return f2bf(a) | (f2bf(b) << 16);
}

// ---------------- single-pass bucket scatter ----------------

__global__ void scatter_direct(const int* __restrict__ src, const int* __restrict__ dst,
                               int* __restrict__ cur, int* __restrict__ pe,
                               int2* __restrict__ ov, int* __restrict__ ovcnt, int E) {
    __shared__ int h[NB];
    __shared__ int base[NB];
    int t = threadIdx.x, b = blockIdx.x;
    h[t] = 0;
    __syncthreads();
    int cbase = b * CH;
    int d[EPT], s[EPT], r[EPT];
#pragma unroll
    for (int j = 0; j < EPT; ++j) {
        int e = cbase + j * BLK + t;
        bool ok = e < E;
        d[j] = ok ? dst[e] : 0;
        s[j] = ok ? src[e] : 0;
        r[j] = ok ? atomicAdd(&h[d[j] >> GSH], 1) : -1;
    }
    __syncthreads();
    base[t] = h[t] ? atomicAdd(&cur[t], h[t]) : 0;
    __syncthreads();
#pragma unroll
    for (int j = 0; j < EPT; ++j) {
        if (r[j] >= 0) {
            int bk = d[j] >> GSH;
            int p = base[bk] + r[j];
            if (p < CMAX) pe[bk * CMAX + p] = ((d[j] & (GSZ - 1)) << 17) | s[j];
            else { int op = atomicAdd(ovcnt, 1); ov[op] = make_int2(d[j], s[j]); }
        }
    }
}

// ---------------- group CSR (one block per 512-node group) ----------------
// In-block scan of cur[256] -> groupBeg; builds dense row_ptr/col, dinv, and
// the prescaled bf16 layer-1 input Xa[N,8]. Drains the overflow list too.

__global__ void group_csr_kernel(const int* __restrict__ pe, const int* __restrict__ cur,
                                 const int2* __restrict__ ov, const int* __restrict__ ovcnt,
                                 int* __restrict__ col, int* __restrict__ row_ptr,
                                 float* __restrict__ dinv, const float* __restrict__ x,
                                 uint4* __restrict__ xa, int N) {
    __shared__ int hist[GSZ];
    __shared__ int scn[GSZ];
    __shared__ int part[256];
    __shared__ int sh_gb, sh_cnt, sh_tot;
    int g = blockIdx.x, t = threadIdx.x;
    // groupBeg via in-block scan of cur[256]
    int c = cur[t];
    part[t] = c;
    __syncthreads();
    for (int off = 1; off < 256; off <<= 1) {
        int v = (t >= off) ? part[t - off] : 0;
        __syncthreads();
        if (t >= off) part[t] += v;
        __syncthreads();
    }
    if (t == g)   { sh_gb = part[t] - c; sh_cnt = c; }
    if (t == 255) sh_tot = part[255];
    __syncthreads();
    int gb = sh_gb, mycnt = sh_cnt;
    int nslot = mycnt < CMAX ? mycnt : CMAX;
    int nov = *ovcnt;   // normally 0
    hist[t] = 0; hist[t + 256] = 0;
    __syncthreads();
    const int* myPe = pe + g * CMAX;
    for (int e = t; e < nslot; e += BLK) atomicAdd(&hist[myPe[e] >> 17], 1);
    for (int i = t; i < nov; i += BLK) {
        int2 v = ov[i];
        if ((v.x >> GSH) == g) atomicAdd(&hist[v.x & (GSZ - 1)], 1);
    }
    __syncthreads();
    // exclusive scan of hist[512]
    int a0 = hist[2 * t], a1 = hist[2 * t + 1];
    int s2 = a0 + a1;
    part[t] = s2;
    __syncthreads();
    for (int off = 1; off < 256; off <<= 1) {
        int v = (t >= off) ? part[t - off] : 0;
        __syncthreads();
        if (t >= off) part[t] += v;
        __syncthreads();
    }
    int excl = part[t] - s2;
    scn[2 * t] = excl;
    scn[2 * t + 1] = excl + a0;
    __syncthreads();
#pragma unroll
    for (int i = t; i < GSZ; i += BLK) {
        int d = (g << GSH) + i;
        if (d < N) {
            row_ptr[d] = gb + scn[i];
            float di = rsqrtf((float)hist[i] + 1.0f);   // +1 self-loop
            dinv[d] = di;
            const float* r = x + (size_t)d * 5;          // fused prescale
            uint4 u;
            u.x = pack2(r[0] * di, r[1] * di);
            u.y = pack2(r[2] * di, r[3] * di);
            u.z = pack2(r[4] * di, 0.f);
            u.w = 0u;
            xa[d] = u;
        }
    }
    if (g == 0 && t == 0) row_ptr[N] = sh_tot;
    __syncthreads();
    hist[t] = scn[t]; hist[t + 256] = scn[t + 256];   // reuse as cursors
    __syncthreads();
    for (int e = t; e < nslot; e += BLK) {
        int v = myPe[e];
        int p = atomicAdd(&hist[v >> 17], 1);
        col[gb + p] = v & 0x1FFFF;
    }
    for (int i = t; i < nov; i += BLK) {
        int2 v = ov[i];
        if ((v.x >> GSH) == g) {
            int p = atomicAdd(&hist[v.x & (GSZ - 1)], 1);
            col[gb + p] = v.y;
        }
    }
}

// ---------------- fused gather + matmul per layer ----------------

template <int F, int FIN, int FOUT, int CAP, bool PRESCALE_OUT>
__global__ void fused_layer_kernel(const int* __restrict__ row_ptr, const int* __restrict__ col,
                                   const uint4* __restrict__ xb, const float* __restrict__ W,
                                   const float* __restrict__ bias, const float* __restrict__ dinv,
                                   uint2* __restrict__ outb, int N) {
    constexpr int TPN = F / 8;
    constexpr int NPB = 256 / TPN;
    constexpr int RQ  = F / 8;
    constexpr int QO  = FOUT / 4;
    constexpr int STR = F + 1;
    __shared__ int lcol[CAP];
    __shared__ int lrp[NPB + 1];
    __shared__ float dl[NPB];
    __shared__ __align__(16) float gl[NPB * STR];
    __shared__ __align__(16) float wl[FIN * FOUT];
    __shared__ __align__(16) float bl[FOUT];
    int t = threadIdx.x;
    int n0 = blockIdx.x * NPB;
    for (int i = t; i <= NPB; i += 256) lrp[i] = row_ptr[min(n0 + i, N)];
    for (int i = t; i < NPB; i += 256) dl[i] = dinv[min(n0 + i, N - 1)];
    for (int i = t; i < FIN * FOUT / 4; i += 256)
        ((float4*)wl)[i] = ((const float4*)W)[i];
    for (int i = t; i < FOUT; i += 256) bl[i] = bias[i];
    __syncthreads();
    int base = lrp[0];
    int total = lrp[NPB] - base;
    int stage = total < CAP ? total : CAP;
    for (int i = t; i < stage; i += 256) lcol[i] = col[base + i];
    __syncthreads();
    {   // phase A: gather (8-deep unroll; latency-bound)
        int ln = t / TPN, q = t % TPN;
        int n = n0 + ln;
        if (n < N) {
            float acc[8];
            uint4 u = xb[(size_t)n * RQ + q];   // self term
            acc[0] = bfu_lo(u.x); acc[1] = bfu_hi(u.x);
            acc[2] = bfu_lo(u.y); acc[3] = bfu_hi(u.y);
            acc[4] = bfu_lo(u.z); acc[5] = bfu_hi(u.z);
            acc[6] = bfu_lo(u.w); acc[7] = bfu_hi(u.w);
            int beg = lrp[ln] - base, end = lrp[ln + 1] - base;
            int stop = end < stage ? end : stage;
            int e = beg;
            for (; e + 7 < stop; e += 8) {
                uint4 uu[8];
#pragma unroll
                for (int j = 0; j < 8; ++j) uu[j] = xb[(size_t)lcol[e + j] * RQ + q];
#pragma unroll
                for (int j = 0; j < 8; ++j) {
                    acc[0] += bfu_lo(uu[j].x); acc[1] += bfu_hi(uu[j].x);
                    acc[2] += bfu_lo(uu[j].y); acc[3] += bfu_hi(uu[j].y);
                    acc[4] += bfu_lo(uu[j].z); acc[5] += bfu_hi(uu[j].z);
                    acc[6] += bfu_lo(uu[j].w); acc[7] += bfu_hi(uu[j].w);
                }
            }
            for (; e + 3 < stop; e += 4) {
                uint4 uu[4];
#pragma unroll
                for (int j = 0; j < 4; ++j) uu[j] = xb[(size_t)lcol[e + j] * RQ + q];
#pragma unroll
                for (int j = 0; j < 4; ++j) {
                    acc[0] += bfu_lo(uu[j].x); acc[1] += bfu_hi(uu[j].x);
                    acc[2] += bfu_lo(uu[j].y); acc[3] += bfu_hi(uu[j].y);
                    acc[4] += bfu_lo(uu[j].z); acc[5] += bfu_hi(uu[j].z);
                    acc[6] += bfu_lo(uu[j].w); acc[7] += bfu_hi(uu[j].w);
                }
            }
            for (; e < end; ++e) {
                int s = (e < stage) ? lcol[e] : col[base + e];   // cold fallback
                uint4 uu = xb[(size_t)s * RQ + q];
                acc[0] += bfu_lo(uu.x); acc[1] += bfu_hi(uu.x);
                acc[2] += bfu_lo(uu.y); acc[3] += bfu_hi(uu.y);
                acc[4] += bfu_lo(uu.z); acc[5] += bfu_hi(uu.z);
                acc[6] += bfu_lo(uu.w); acc[7] += bfu_hi(uu.w);
            }
            float* gr = gl + ln * STR + q * 8;
#pragma unroll
            for (int j = 0; j < 8; ++j) gr[j] = acc[j];
        }
    }
    __syncthreads();
    // phase B: matmul from LDS
    for (int task = t; task < NPB * QO; task += 256) {
        int ln2 = task / QO, qq = task % QO;
        int n2 = n0 + ln2;
        if (n2 >= N) continue;
        float di = dl[ln2];
        const float* row = gl + ln2 * STR;
        float4 acc = make_float4(0.f, 0.f, 0.f, 0.f);
#pragma unroll
        for (int k = 0; k < FIN; ++k) {
            float rk = row[k];
            float4 wk = *(const float4*)(wl + k * FOUT + 4 * qq);
            acc.x = fmaf(rk, wk.x, acc.x);
            acc.y = fmaf(rk, wk.y, acc.y);
            acc.z = fmaf(rk, wk.z, acc.z);
            acc.w = fmaf(rk, wk.w, acc.w);
        }
        float4 bq = *(const float4*)(bl + 4 * qq);
        float4 v;
        v.x = fmaxf(di * acc.x + bq.x, 0.f);
        v.y = fmaxf(di * acc.y + bq.y, 0.f);
        v.z = fmaxf(di * acc.z + bq.z, 0.f);
        v.w = fmaxf(di * acc.w + bq.w, 0.f);
        if (PRESCALE_OUT) { v.x *= di; v.y *= di; v.z *= di; v.w *= di; }
        uint2 o;
        o.x = pack2(v.x, v.y);
        o.y = pack2(v.z, v.w);
        outb[(size_t)n2 * QO + qq] = o;
    }
}

// ---------------- pool + head (atomic-free, bf16 input) ----------------

__global__ void bounds_kernel(const int* __restrict__ batch, int* __restrict__ start,
                              int N, int G) {
    int g = blockIdx.x * blockDim.x + threadIdx.x;
    if (g > G) return;
    if (g == G) { start[G] = N; return; }
    int lo = 0, hi = N;
    while (lo < hi) {
        int mid = (lo + hi) >> 1;
        if (batch[mid] < g) lo = mid + 1; else hi = mid;
    }
    start[g] = lo;
}

__global__ void pool_head_kernel(const unsigned int* __restrict__ h, const int* __restrict__ start,
                                 const float* __restrict__ Wfc, const float* __restrict__ bfc,
                                 float* __restrict__ out) {
    __shared__ float part[8][64];
    int g = blockIdx.x;
    int t = threadIdx.x;          // 256
    int u = t & 31, w = t >> 5;
    int s = start[g], e = start[g + 1];
    float a0 = 0.f, a1 = 0.f;
    for (int n = s + w; n < e; n += 8) {
        unsigned int word = h[(size_t)n * 32 + u];
        a0 += bfu_lo(word);
        a1 += bfu_hi(word);
    }
    part[w][2 * u]     = a0;
    part[w][2 * u + 1] = a1;
    __syncthreads();
    if (t < 64) {
        float p = 0.f;
#pragma unroll
        for (int w2 = 0; w2 < 8; ++w2) p += part[w2][t];
        p /= fmaxf((float)(e - s), 1.0f);
        float l0 = p * Wfc[t * 2 + 0];
        float l1 = p * Wfc[t * 2 + 1];
#pragma unroll
        for (int off = 32; off; off >>= 1) {
            l0 += __shfl_down(l0, off);
            l1 += __shfl_down(l1, off);
        }
        if (t == 0) {
            l0 += bfc[0]; l1 += bfc[1];
            float m   = fmaxf(l0, l1);
            float lse = m + logf(expf(l0 - m) + expf(l1 - m));
            out[g * 2 + 0] = l0 - lse;
            out[g * 2 + 1] = l1 - lse;
        }
    }
}

// ---------------- driver ----------------

extern "C" void kernel_launch(void* const* d_in, const int* in_sizes, int n_in,
                              void* d_out, int out_size, void* d_ws, size_t ws_size,
                              hipStream_t stream) {
    const float* x     = (const float*)d_in[0];
    const int*   src   = (const int*)d_in[1];
    const int*   dst   = (const int*)d_in[2];
    const int*   batch = (const int*)d_in[3];
    const float* W1    = (const float*)d_in[4];
    const float* b1    = (const float*)d_in[5];
    const float* W2    = (const float*)d_in[6];
    const float* b2    = (const float*)d_in[7];
    const float* W3    = (const float*)d_in[8];
    const float* b3    = (const float*)d_in[9];
    const float* Wfc   = (const float*)d_in[10];
    const float* bfc   = (const float*)d_in[11];
    float* out = (float*)d_out;

    const int N = in_sizes[0] / 5;   // 100000 (< 2^17 for packed edges)
    const int E = in_sizes[1];       // 1600000
    const int G = out_size / 2;      // 1024

    const int nChunks = (E + CH - 1) / CH;           // 391
    const int nGroups = (N + GSZ - 1) >> GSH;        // 196

    // workspace layout (4B units; all offsets 16B-aligned)
    int* row_ptr  = (int*)d_ws;                   // N+4 (uses N+1)
    int* col      = row_ptr + N + 4;              // E
    int* cur      = col + E;                      // 256 + 4 (cur[256], ovcnt at +256)
    int* ovcnt    = cur + 256;                    // 1 (in the padded 4)
    int* start    = cur + 260;                    // G+8 (uses G+1)
    float* dinv   = (float*)(start + G + 8);      // N
    int*   Xa     = (int*)(dinv + N);             // N*16 ints: Xs1[N,8] / Xs3[N,32] bf16
    int*   Xb     = Xa + (size_t)N * 16;          // N*8  ints: Xs2[N,16] bf16
    int*   H3b    = Xb + (size_t)N * 8;           // N*32 ints: out3[N,64] bf16
    int*   pe     = H3b + (size_t)N * 32;         // NB*CMAX = 2M ints (8MB)
    int2*  ov     = (int2*)H3b;                   // E int2 (aliases H3b; dead before L3)
    // total ~ 46 MB

    auto blocks = [](long n) { return (int)((n + BLK - 1) / BLK); };

    // ---- CSR build: one edge pass + per-group pass ----
    hipMemsetAsync(cur, 0, 260 * sizeof(int), stream);
    scatter_direct<<<nChunks, 256, 0, stream>>>(src, dst, cur, pe, ov, ovcnt, E);
    bounds_kernel<<<blocks(G + 1), BLK, 0, stream>>>(batch, start, N, G);
    group_csr_kernel<<<nGroups, 256, 0, stream>>>(pe, cur, ov, ovcnt, col, row_ptr,
                                                  dinv, x, (uint4*)Xa, N);

    // ---- layer 1: Xa[N,8] -> Xb[N,16]   (F=8: 256 nodes/block) ----
    fused_layer_kernel<8, 5, 16, 6144, true><<<(N + 255) / 256, 256, 0, stream>>>(
        row_ptr, col, (const uint4*)Xa, W1, b1, dinv, (uint2*)Xb, N);

    // ---- layer 2: Xb[N,16] -> Xa[N,32]  (F=16: 128 nodes/block) ----
    fused_layer_kernel<16, 16, 32, 4096, true><<<(N + 127) / 128, 256, 0, stream>>>(
        row_ptr, col, (const uint4*)Xb, W2, b2, dinv, (uint2*)Xa, N);

    // ---- layer 3: Xa[N,32] -> H3b[N,64] (F=32: 64 nodes/block) ----
    fused_layer_kernel<32, 32, 64, 2048, false><<<(N + 63) / 64, 256, 0, stream>>>(
        row_ptr, col, (const uint4*)Xa, W3, b3, dinv, (uint2*)H3b, N);

    // ---- mean pool + head (no atomics, bf16 input) ----
    pool_head_kernel<<<G, 256, 0, stream>>>((const unsigned int*)H3b, start, Wfc, bfc, out);
}

// Round 11
// 150.176 us; speedup vs baseline: 1.0300x; 1.0300x over previous
//
#include <hip/hip_runtime.h>

// GNN_17575006175684: 3-layer GCN + mean-pool + linear head + log_softmax.
// R11 = R10 with the runtime hipMemsetAsync removed from the timed path:
// R10's 1KB cur-memset became a graph-replayed fillBuffer dispatch costing
// ~43us/replay (rocprof: fill dur 43us, ~0 HBM bytes). The zeroing of
// cur[256]+ovcnt is now fused into bounds_kernel (launched first, depends
// only on batch). 7 dispatches, no fills:
//   bounds(+zero) -> scatter_direct -> group_csr -> 3x fused_layer -> pool_head
// Everything else identical to R10: single-pass bucket scatter (chunk-level
// reservation, CMAX=8192 + unconditional overflow path), in-block groupBeg
// scan, packed 4B edges, fused prescale, fused gather+matmul (bf16 tables,
// fp32 accum), atomic-free pool+head.

#define BLK 256
#define CH 4096             // edges per chunk
#define EPT (CH / BLK)      // 16
#define NB 256              // buckets = dst>>9 (512 nodes each)
#define GSH 9
#define GSZ 512
#define CMAX 8192           // bucket slot capacity (mean 6250)

// ---------------- bf16 helpers (storage only) ----------------

__device__ inline float bfu_lo(unsigned int w) { return __uint_as_float(w << 16); }
__device__ inline float bfu_hi(unsigned int w) { return __uint_as_float(w & 0xffff0000u); }
__device__ inline unsigned int f2bf(float f) {   // RNE
    unsigned int w = __float_as_uint(f);
    return (w + 0x7fffu + ((w >> 16) & 1u)) >> 16;
}
__device__ inline unsigned int pack2(float a, float b) {
    return f2bf(a) | (f2bf(b) << 16);
}

// ---------------- bounds + zero (first dispatch) ----------------

__global__ void bounds_zero_kernel(const int* __restrict__ batch, int* __restrict__ start,
                                   int* __restrict__ cur, int N, int G) {
    int g = blockIdx.x * blockDim.x + threadIdx.x;
    if (g < 260) cur[g] = 0;   // cur[256] + ovcnt + pad
    if (g > G) return;
    if (g == G) { start[G] = N; return; }
    int lo = 0, hi = N;
    while (lo < hi) {
        int mid = (lo + hi) >> 1;
        if (batch[mid] < g) lo = mid + 1; else hi = mid;
    }
    start[g] = lo;
}

// ---------------- single-pass bucket scatter ----------------

__global__ void scatter_direct(const int* __restrict__ src, const int* __restrict__ dst,
                               int* __restrict__ cur, int* __restrict__ pe,
                               int2* __restrict__ ov, int* __restrict__ ovcnt, int E) {
    __shared__ int h[NB];
    __shared__ int base[NB];
    int t = threadIdx.x, b = blockIdx.x;
    h[t] = 0;
    __syncthreads();
    int cbase = b * CH;
    int d[EPT], s[EPT], r[EPT];
#pragma unroll
    for (int j = 0; j < EPT; ++j) {
        int e = cbase + j * BLK + t;
        bool ok = e < E;
        d[j] = ok ? dst[e] : 0;
        s[j] = ok ? src[e] : 0;
        r[j] = ok ? atomicAdd(&h[d[j] >> GSH], 1) : -1;
    }
    __syncthreads();
    base[t] = h[t] ? atomicAdd(&cur[t], h[t]) : 0;
    __syncthreads();
#pragma unroll
    for (int j = 0; j < EPT; ++j) {
        if (r[j] >= 0) {
            int bk = d[j] >> GSH;
            int p = base[bk] + r[j];
            if (p < CMAX) pe[bk * CMAX + p] = ((d[j] & (GSZ - 1)) << 17) | s[j];
            else { int op = atomicAdd(ovcnt, 1); ov[op] = make_int2(d[j], s[j]); }
        }
    }
}

// ---------------- group CSR (one block per 512-node group) ----------------

__global__ void group_csr_kernel(const int* __restrict__ pe, const int* __restrict__ cur,
                                 const int2* __restrict__ ov, const int* __restrict__ ovcnt,
                                 int* __restrict__ col, int* __restrict__ row_ptr,
                                 float* __restrict__ dinv, const float* __restrict__ x,
                                 uint4* __restrict__ xa, int N) {
    __shared__ int hist[GSZ];
    __shared__ int scn[GSZ];
    __shared__ int part[256];
    __shared__ int sh_gb, sh_cnt, sh_tot;
    int g = blockIdx.x, t = threadIdx.x;
    // groupBeg via in-block scan of cur[256]
    int c = cur[t];
    part[t] = c;
    __syncthreads();
    for (int off = 1; off < 256; off <<= 1) {
        int v = (t >= off) ? part[t - off] : 0;
        __syncthreads();
        if (t >= off) part[t] += v;
        __syncthreads();
    }
    if (t == g)   { sh_gb = part[t] - c; sh_cnt = c; }
    if (t == 255) sh_tot = part[255];
    __syncthreads();
    int gb = sh_gb, mycnt = sh_cnt;
    int nslot = mycnt < CMAX ? mycnt : CMAX;
    int nov = *ovcnt;   // normally 0
    hist[t] = 0; hist[t + 256] = 0;
    __syncthreads();
    const int* myPe = pe + g * CMAX;
    for (int e = t; e < nslot; e += BLK) atomicAdd(&hist[myPe[e] >> 17], 1);
    for (int i = t; i < nov; i += BLK) {
        int2 v = ov[i];
        if ((v.x >> GSH) == g) atomicAdd(&hist[v.x & (GSZ - 1)], 1);
    }
    __syncthreads();
    // exclusive scan of hist[512]
    int a0 = hist[2 * t], a1 = hist[2 * t + 1];
    int s2 = a0 + a1;
    part[t] = s2;
    __syncthreads();
    for (int off = 1; off < 256; off <<= 1) {
        int v = (t >= off) ? part[t - off] : 0;
        __syncthreads();
        if (t >= off) part[t] += v;
        __syncthreads();
    }
    int excl = part[t] - s2;
    scn[2 * t] = excl;
    scn[2 * t + 1] = excl + a0;
    __syncthreads();
#pragma unroll
    for (int i = t; i < GSZ; i += BLK) {
        int d = (g << GSH) + i;
        if (d < N) {
            row_ptr[d] = gb + scn[i];
            float di = rsqrtf((float)hist[i] + 1.0f);   // +1 self-loop
            dinv[d] = di;
            const float* r = x + (size_t)d * 5;          // fused prescale
            uint4 u;
            u.x = pack2(r[0] * di, r[1] * di);
            u.y = pack2(r[2] * di, r[3] * di);
            u.z = pack2(r[4] * di, 0.f);
            u.w = 0u;
            xa[d] = u;
        }
    }
    if (g == 0 && t == 0) row_ptr[N] = sh_tot;
    __syncthreads();
    hist[t] = scn[t]; hist[t + 256] = scn[t + 256];   // reuse as cursors
    __syncthreads();
    for (int e = t; e < nslot; e += BLK) {
        int v = myPe[e];
        int p = atomicAdd(&hist[v >> 17], 1);
        col[gb + p] = v & 0x1FFFF;
    }
    for (int i = t; i < nov; i += BLK) {
        int2 v = ov[i];
        if ((v.x >> GSH) == g) {
            int p = atomicAdd(&hist[v.x & (GSZ - 1)], 1);
            col[gb + p] = v.y;
        }
    }
}

// ---------------- fused gather + matmul per layer ----------------

template <int F, int FIN, int FOUT, int CAP, bool PRESCALE_OUT>
__global__ void fused_layer_kernel(const int* __restrict__ row_ptr, const int* __restrict__ col,
                                   const uint4* __restrict__ xb, const float* __restrict__ W,
                                   const float* __restrict__ bias, const float* __restrict__ dinv,
                                   uint2* __restrict__ outb, int N) {
    constexpr int TPN = F / 8;
    constexpr int NPB = 256 / TPN;
    constexpr int RQ  = F / 8;
    constexpr int QO  = FOUT / 4;
    constexpr int STR = F + 1;
    __shared__ int lcol[CAP];
    __shared__ int lrp[NPB + 1];
    __shared__ float dl[NPB];
    __shared__ __align__(16) float gl[NPB * STR];
    __shared__ __align__(16) float wl[FIN * FOUT];
    __shared__ __align__(16) float bl[FOUT];
    int t = threadIdx.x;
    int n0 = blockIdx.x * NPB;
    for (int i = t; i <= NPB; i += 256) lrp[i] = row_ptr[min(n0 + i, N)];
    for (int i = t; i < NPB; i += 256) dl[i] = dinv[min(n0 + i, N - 1)];
    for (int i = t; i < FIN * FOUT / 4; i += 256)
        ((float4*)wl)[i] = ((const float4*)W)[i];
    for (int i = t; i < FOUT; i += 256) bl[i] = bias[i];
    __syncthreads();
    int base = lrp[0];
    int total = lrp[NPB] - base;
    int stage = total < CAP ? total : CAP;
    for (int i = t; i < stage; i += 256) lcol[i] = col[base + i];
    __syncthreads();
    {   // phase A: gather (8-deep unroll; latency-bound)
        int ln = t / TPN, q = t % TPN;
        int n = n0 + ln;
        if (n < N) {
            float acc[8];
            uint4 u = xb[(size_t)n * RQ + q];   // self term
            acc[0] = bfu_lo(u.x); acc[1] = bfu_hi(u.x);
            acc[2] = bfu_lo(u.y); acc[3] = bfu_hi(u.y);
            acc[4] = bfu_lo(u.z); acc[5] = bfu_hi(u.z);
            acc[6] = bfu_lo(u.w); acc[7] = bfu_hi(u.w);
            int beg = lrp[ln] - base, end = lrp[ln + 1] - base;
            int stop = end < stage ? end : stage;
            int e = beg;
            for (; e + 7 < stop; e += 8) {
                uint4 uu[8];
#pragma unroll
                for (int j = 0; j < 8; ++j) uu[j] = xb[(size_t)lcol[e + j] * RQ + q];
#pragma unroll
                for (int j = 0; j < 8; ++j) {
                    acc[0] += bfu_lo(uu[j].x); acc[1] += bfu_hi(uu[j].x);
                    acc[2] += bfu_lo(uu[j].y); acc[3] += bfu_hi(uu[j].y);
                    acc[4] += bfu_lo(uu[j].z); acc[5] += bfu_hi(uu[j].z);
                    acc[6] += bfu_lo(uu[j].w); acc[7] += bfu_hi(uu[j].w);
                }
            }
            for (; e + 3 < stop; e += 4) {
                uint4 uu[4];
#pragma unroll
                for (int j = 0; j < 4; ++j) uu[j] = xb[(size_t)lcol[e + j] * RQ + q];
#pragma unroll
                for (int j = 0; j < 4; ++j) {
                    acc[0] += bfu_lo(uu[j].x); acc[1] += bfu_hi(uu[j].x);
                    acc[2] += bfu_lo(uu[j].y); acc[3] += bfu_hi(uu[j].y);
                    acc[4] += bfu_lo(uu[j].z); acc[5] += bfu_hi(uu[j].z);
                    acc[6] += bfu_lo(uu[j].w); acc[7] += bfu_hi(uu[j].w);
                }
            }
            for (; e < end; ++e) {
                int s = (e < stage) ? lcol[e] : col[base + e];   // cold fallback
                uint4 uu = xb[(size_t)s * RQ + q];
                acc[0] += bfu_lo(uu.x); acc[1] += bfu_hi(uu.x);
                acc[2] += bfu_lo(uu.y); acc[3] += bfu_hi(uu.y);
                acc[4] += bfu_lo(uu.z); acc[5] += bfu_hi(uu.z);
                acc[6] += bfu_lo(uu.w); acc[7] += bfu_hi(uu.w);
            }
            float* gr = gl + ln * STR + q * 8;
#pragma unroll
            for (int j = 0; j < 8; ++j) gr[j] = acc[j];
        }
    }
    __syncthreads();
    // phase B: matmul from LDS
    for (int task = t; task < NPB * QO; task += 256) {
        int ln2 = task / QO, qq = task % QO;
        int n2 = n0 + ln2;
        if (n2 >= N) continue;
        float di = dl[ln2];
        const float* row = gl + ln2 * STR;
        float4 acc = make_float4(0.f, 0.f, 0.f, 0.f);
#pragma unroll
        for (int k = 0; k < FIN; ++k) {
            float rk = row[k];
            float4 wk = *(const float4*)(wl + k * FOUT + 4 * qq);
            acc.x = fmaf(rk, wk.x, acc.x);
            acc.y = fmaf(rk, wk.y, acc.y);
            acc.z = fmaf(rk, wk.z, acc.z);
            acc.w = fmaf(rk, wk.w, acc.w);
        }
        float4 bq = *(const float4*)(bl + 4 * qq);
        float4 v;
        v.x = fmaxf(di * acc.x + bq.x, 0.f);
        v.y = fmaxf(di * acc.y + bq.y, 0.f);
        v.z = fmaxf(di * acc.z + bq.z, 0.f);
        v.w = fmaxf(di * acc.w + bq.w, 0.f);
        if (PRESCALE_OUT) { v.x *= di; v.y *= di; v.z *= di; v.w *= di; }
        uint2 o;
        o.x = pack2(v.x, v.y);
        o.y = pack2(v.z, v.w);
        outb[(size_t)n2 * QO + qq] = o;
    }
}

// ---------------- pool + head (atomic-free, bf16 input) ----------------

__global__ void pool_head_kernel(const unsigned int* __restrict__ h, const int* __restrict__ start,
                                 const float* __restrict__ Wfc, const float* __restrict__ bfc,
                                 float* __restrict__ out) {
    __shared__ float part[8][64];
    int g = blockIdx.x;
    int t = threadIdx.x;          // 256
    int u = t & 31, w = t >> 5;
    int s = start[g], e = start[g + 1];
    float a0 = 0.f, a1 = 0.f;
    for (int n = s + w; n < e; n += 8) {
        unsigned int word = h[(size_t)n * 32 + u];
        a0 += bfu_lo(word);
        a1 += bfu_hi(word);
    }
    part[w][2 * u]     = a0;
    part[w][2 * u + 1] = a1;
    __syncthreads();
    if (t < 64) {
        float p = 0.f;
#pragma unroll
        for (int w2 = 0; w2 < 8; ++w2) p += part[w2][t];
        p /= fmaxf((float)(e - s), 1.0f);
        float l0 = p * Wfc[t * 2 + 0];
        float l1 = p * Wfc[t * 2 + 1];
#pragma unroll
        for (int off = 32; off; off >>= 1) {
            l0 += __shfl_down(l0, off);
            l1 += __shfl_down(l1, off);
        }
        if (t == 0) {
            l0 += bfc[0]; l1 += bfc[1];
            float m   = fmaxf(l0, l1);
            float lse = m + logf(expf(l0 - m) + expf(l1 - m));
            out[g * 2 + 0] = l0 - lse;
            out[g * 2 + 1] = l1 - lse;
        }
    }
}

// ---------------- driver ----------------

extern "C" void kernel_launch(void* const* d_in, const int* in_sizes, int n_in,
                              void* d_out, int out_size, void* d_ws, size_t ws_size,
                              hipStream_t stream) {
    const float* x     = (const float*)d_in[0];
    const int*   src   = (const int*)d_in[1];
    const int*   dst   = (const int*)d_in[2];
    const int*   batch = (const int*)d_in[3];
    const float* W1    = (const float*)d_in[4];
    const float* b1    = (const float*)d_in[5];
    const float* W2    = (const float*)d_in[6];
    const float* b2    = (const float*)d_in[7];
    const float* W3    = (const float*)d_in[8];
    const float* b3    = (const float*)d_in[9];
    const float* Wfc   = (const float*)d_in[10];
    const float* bfc   = (const float*)d_in[11];
    float* out = (float*)d_out;

    const int N = in_sizes[0] / 5;   // 100000 (< 2^17 for packed edges)
    const int E = in_sizes[1];       // 1600000
    const int G = out_size / 2;      // 1024

    const int nChunks = (E + CH - 1) / CH;           // 391
    const int nGroups = (N + GSZ - 1) >> GSH;        // 196

    // workspace layout (4B units; all offsets 16B-aligned)
    int* row_ptr  = (int*)d_ws;                   // N+4 (uses N+1)
    int* col      = row_ptr + N + 4;              // E
    int* cur      = col + E;                      // 256 + 4 (cur[256], ovcnt at +256)
    int* ovcnt    = cur + 256;                    // 1 (in the padded 4)
    int* start    = cur + 260;                    // G+8 (uses G+1)
    float* dinv   = (float*)(start + G + 8);      // N
    int*   Xa     = (int*)(dinv + N);             // N*16 ints: Xs1[N,8] / Xs3[N,32] bf16
    int*   Xb     = Xa + (size_t)N * 16;          // N*8  ints: Xs2[N,16] bf16
    int*   H3b    = Xb + (size_t)N * 8;           // N*32 ints: out3[N,64] bf16
    int*   pe     = H3b + (size_t)N * 32;         // NB*CMAX = 2M ints (8MB)
    int2*  ov     = (int2*)H3b;                   // E int2 (aliases H3b; dead before L3)
    // total ~ 46 MB

    auto blocks = [](long n) { return (int)((n + BLK - 1) / BLK); };

    // ---- bounds + zero cur/ovcnt (no runtime memset!) ----
    bounds_zero_kernel<<<blocks(G + 1), BLK, 0, stream>>>(batch, start, cur, N, G);

    // ---- CSR build: one edge pass + per-group pass ----
    scatter_direct<<<nChunks, 256, 0, stream>>>(src, dst, cur, pe, ov, ovcnt, E);
    group_csr_kernel<<<nGroups, 256, 0, stream>>>(pe, cur, ov, ovcnt, col, row_ptr,
                                                  dinv, x, (uint4*)Xa, N);

    // ---- layer 1: Xa[N,8] -> Xb[N,16]   (F=8: 256 nodes/block) ----
    fused_layer_kernel<8, 5, 16, 6144, true><<<(N + 255) / 256, 256, 0, stream>>>(
        row_ptr, col, (const uint4*)Xa, W1, b1, dinv, (uint2*)Xb, N);

    // ---- layer 2: Xb[N,16] -> Xa[N,32]  (F=16: 128 nodes/block) ----
    fused_layer_kernel<16, 16, 32, 4096, true><<<(N + 127) / 128, 256, 0, stream>>>(
        row_ptr, col, (const uint4*)Xb, W2, b2, dinv, (uint2*)Xa, N);

    // ---- layer 3: Xa[N,32] -> H3b[N,64] (F=32: 64 nodes/block) ----
    fused_layer_kernel<32, 32, 64, 2048, false><<<(N + 63) / 64, 256, 0, stream>>>(
        row_ptr, col, (const uint4*)Xa, W3, b3, dinv, (uint2*)H3b, N);

    // ---- mean pool + head (no atomics, bf16 input) ----
    pool_head_kernel<<<G, 256, 0, stream>>>((const unsigned int*)H3b, start, Wfc, bfc, out);
}

// Round 12
// 129.157 us; speedup vs baseline: 1.1976x; 1.1627x over previous
//
#include <hip/hip_runtime.h>

// GNN_17575006175684: 3-layer GCN + mean-pool + linear head + log_softmax.
// R12 = revert to R9's proven CSR front-end (131us) after R10/R11's
// single-pass scatter regressed (~+20us: burst LDS atomics with no
// interleaved global work can't hide latency; R9's scatter1 interleaves
// atomic+store per edge). Kept from R10/R11: 8-deep gather unroll, dinv in
// LDS for matmul phase. Pipeline:
//   hist1 -> seg_scan -> bucket_scan -> scatter1(packed 4B edges)
//   -> group_csr (row_ptr/col/dinv + fused bf16 prescale of x)
//   -> 3x fused gather+matmul layers (bf16 tables, fp32 accum, LDS staging)
//   -> atomic-free pool+head.  No runtime memsets. 10 dispatches.

#define BLK 256
#define CH 4096             // edges per chunk in pass 1
#define EPT (CH / BLK)      // 16
#define NB 256              // pass-1 buckets = dst>>9 (512 nodes each)
#define GSH 9
#define GSZ 512

// ---------------- bf16 helpers (storage only) ----------------

__device__ inline float bfu_lo(unsigned int w) { return __uint_as_float(w << 16); }
__device__ inline float bfu_hi(unsigned int w) { return __uint_as_float(w & 0xffff0000u); }
__device__ inline unsigned int f2bf(float f) {   // RNE
    unsigned int w = __float_as_uint(f);
    return (w + 0x7fffu + ((w >> 16) & 1u)) >> 16;
}
__device__ inline unsigned int pack2(float a, float b) {
    return f2bf(a) | (f2bf(b) << 16);
}

// ---------------- pass 1: coarse bucket by dst>>9 ----------------

__global__ void hist1_kernel(const int* __restrict__ dst, int* __restrict__ cnt,
                             int E, int nChunks) {
    __shared__ int h[NB];
    int t = threadIdx.x, b = blockIdx.x;
    h[t] = 0;
    __syncthreads();
    int base = b * CH;
#pragma unroll
    for (int j = 0; j < EPT; ++j) {
        int e = base + j * BLK + t;
        if (e < E) atomicAdd(&h[dst[e] >> GSH], 1);
    }
    __syncthreads();
    cnt[(size_t)t * nChunks + b] = h[t];   // bucket-major
}

__global__ void seg_scan_kernel(int* __restrict__ cnt, int* __restrict__ bucketTot,
                                int nChunks) {
    __shared__ int part[256];
    int b = blockIdx.x, t = threadIdx.x;
    size_t base = (size_t)b * nChunks;
    int per = (nChunks + 255) / 256;
    int lo = t * per, hi = lo + per < nChunks ? lo + per : nChunks;
    int sum = 0;
    for (int i = lo; i < hi; ++i) sum += cnt[base + i];
    part[t] = sum;
    __syncthreads();
    for (int off = 1; off < 256; off <<= 1) {
        int x = (t >= off) ? part[t - off] : 0;
        __syncthreads();
        if (t >= off) part[t] += x;
        __syncthreads();
    }
    int run = part[t] - sum;   // exclusive
    for (int i = lo; i < hi; ++i) { int v = cnt[base + i]; cnt[base + i] = run; run += v; }
    if (t == 255) bucketTot[b] = part[255];
}

__global__ void bucket_scan_kernel(const int* __restrict__ bucketTot,
                                   int* __restrict__ groupBeg, int E) {
    __shared__ int part[256];
    int t = threadIdx.x;
    int v = bucketTot[t];
    part[t] = v;
    __syncthreads();
    for (int off = 1; off < 256; off <<= 1) {
        int x = (t >= off) ? part[t - off] : 0;
        __syncthreads();
        if (t >= off) part[t] += x;
        __syncthreads();
    }
    groupBeg[t] = part[t] - v;   // exclusive
    if (t == 0) groupBeg[NB] = E;
}

// packed edge: (dst&511)<<17 | src   (requires src < 2^17; N=100000 ok)
__global__ void scatter1_kernel(const int* __restrict__ src, const int* __restrict__ dst,
                                const int* __restrict__ cnt, const int* __restrict__ groupBeg,
                                int* __restrict__ pe, int E, int nChunks) {
    __shared__ int offs[NB];
    int t = threadIdx.x, b = blockIdx.x;
    offs[t] = cnt[(size_t)t * nChunks + b] + groupBeg[t];
    __syncthreads();
    int base = b * CH;
#pragma unroll
    for (int j = 0; j < EPT; ++j) {
        int e = base + j * BLK + t;
        if (e < E) {
            int d = dst[e];
            int p = atomicAdd(&offs[d >> GSH], 1);
            pe[p] = ((d & (GSZ - 1)) << 17) | src[e];
        }
    }
}

// ---------------- pass 2: one block per 512-node group ----------------
// builds row_ptr/col, dinv, AND the prescaled bf16 layer-1 input Xa[N,8].

__global__ void group_csr_kernel(const int* __restrict__ pe, const int* __restrict__ groupBeg,
                                 int* __restrict__ col, int* __restrict__ row_ptr,
                                 float* __restrict__ dinv, const float* __restrict__ x,
                                 uint4* __restrict__ xa, int N, int E) {
    __shared__ int hist[GSZ];
    __shared__ int scn[GSZ];
    __shared__ int part[256];
    int g = blockIdx.x, t = threadIdx.x;
    hist[t] = 0; hist[t + 256] = 0;
    __syncthreads();
    int lo = groupBeg[g], hi = groupBeg[g + 1];
    for (int e = lo + t; e < hi; e += BLK)
        atomicAdd(&hist[pe[e] >> 17], 1);
    __syncthreads();
    int a0 = hist[2 * t], a1 = hist[2 * t + 1];
    int s2 = a0 + a1;
    part[t] = s2;
    __syncthreads();
    for (int off = 1; off < 256; off <<= 1) {
        int xx = (t >= off) ? part[t - off] : 0;
        __syncthreads();
        if (t >= off) part[t] += xx;
        __syncthreads();
    }
    int excl = part[t] - s2;
    scn[2 * t] = excl;
    scn[2 * t + 1] = excl + a0;
    __syncthreads();
#pragma unroll
    for (int i = t; i < GSZ; i += BLK) {
        int d = (g << GSH) + i;
        if (d < N) {
            row_ptr[d] = lo + scn[i];
            float di = rsqrtf((float)hist[i] + 1.0f);   // +1 self-loop
            dinv[d] = di;
            const float* r = x + (size_t)d * 5;          // fused prescale
            uint4 u;
            u.x = pack2(r[0] * di, r[1] * di);
            u.y = pack2(r[2] * di, r[3] * di);
            u.z = pack2(r[4] * di, 0.f);
            u.w = 0u;
            xa[d] = u;
        }
    }
    if (g == 0 && t == 0) row_ptr[N] = E;
    __syncthreads();
    hist[t] = scn[t]; hist[t + 256] = scn[t + 256];   // reuse as cursors
    __syncthreads();
    for (int e = lo + t; e < hi; e += BLK) {
        int v = pe[e];
        int p = atomicAdd(&hist[v >> 17], 1);
        col[lo + p] = v & 0x1FFFF;   // within this block's window only
    }
}

// ---------------- fused gather + matmul per layer ----------------

template <int F, int FIN, int FOUT, int CAP, bool PRESCALE_OUT>
__global__ void fused_layer_kernel(const int* __restrict__ row_ptr, const int* __restrict__ col,
                                   const uint4* __restrict__ xb, const float* __restrict__ W,
                                   const float* __restrict__ bias, const float* __restrict__ dinv,
                                   uint2* __restrict__ outb, int N) {
    constexpr int TPN = F / 8;
    constexpr int NPB = 256 / TPN;
    constexpr int RQ  = F / 8;
    constexpr int QO  = FOUT / 4;
    constexpr int STR = F + 1;
    __shared__ int lcol[CAP];
    __shared__ int lrp[NPB + 1];
    __shared__ float dl[NPB];
    __shared__ __align__(16) float gl[NPB * STR];
    __shared__ __align__(16) float wl[FIN * FOUT];
    __shared__ __align__(16) float bl[FOUT];
    int t = threadIdx.x;
    int n0 = blockIdx.x * NPB;
    for (int i = t; i <= NPB; i += 256) lrp[i] = row_ptr[min(n0 + i, N)];
    for (int i = t; i < NPB; i += 256) dl[i] = dinv[min(n0 + i, N - 1)];
    for (int i = t; i < FIN * FOUT / 4; i += 256)
        ((float4*)wl)[i] = ((const float4*)W)[i];
    for (int i = t; i < FOUT; i += 256) bl[i] = bias[i];
    __syncthreads();
    int base = lrp[0];
    int total = lrp[NPB] - base;
    int stage = total < CAP ? total : CAP;
    for (int i = t; i < stage; i += 256) lcol[i] = col[base + i];
    __syncthreads();
    {   // phase A: gather (8-deep unroll; latency-bound)
        int ln = t / TPN, q = t % TPN;
        int n = n0 + ln;
        if (n < N) {
            float acc[8];
            uint4 u = xb[(size_t)n * RQ + q];   // self term
            acc[0] = bfu_lo(u.x); acc[1] = bfu_hi(u.x);
            acc[2] = bfu_lo(u.y); acc[3] = bfu_hi(u.y);
            acc[4] = bfu_lo(u.z); acc[5] = bfu_hi(u.z);
            acc[6] = bfu_lo(u.w); acc[7] = bfu_hi(u.w);
            int beg = lrp[ln] - base, end = lrp[ln + 1] - base;
            int stop = end < stage ? end : stage;
            int e = beg;
            for (; e + 7 < stop; e += 8) {
                uint4 uu[8];
#pragma unroll
                for (int j = 0; j < 8; ++j) uu[j] = xb[(size_t)lcol[e + j] * RQ + q];
#pragma unroll
                for (int j = 0; j < 8; ++j) {
                    acc[0] += bfu_lo(uu[j].x); acc[1] += bfu_hi(uu[j].x);
                    acc[2] += bfu_lo(uu[j].y); acc[3] += bfu_hi(uu[j].y);
                    acc[4] += bfu_lo(uu[j].z); acc[5] += bfu_hi(uu[j].z);
                    acc[6] += bfu_lo(uu[j].w); acc[7] += bfu_hi(uu[j].w);
                }
            }
            for (; e + 3 < stop; e += 4) {
                uint4 uu[4];
#pragma unroll
                for (int j = 0; j < 4; ++j) uu[j] = xb[(size_t)lcol[e + j] * RQ + q];
#pragma unroll
                for (int j = 0; j < 4; ++j) {
                    acc[0] += bfu_lo(uu[j].x); acc[1] += bfu_hi(uu[j].x);
                    acc[2] += bfu_lo(uu[j].y); acc[3] += bfu_hi(uu[j].y);
                    acc[4] += bfu_lo(uu[j].z); acc[5] += bfu_hi(uu[j].z);
                    acc[6] += bfu_lo(uu[j].w); acc[7] += bfu_hi(uu[j].w);
                }
            }
            for (; e < end; ++e) {
                int s = (e < stage) ? lcol[e] : col[base + e];   // cold fallback
                uint4 uu = xb[(size_t)s * RQ + q];
                acc[0] += bfu_lo(uu.x); acc[1] += bfu_hi(uu.x);
                acc[2] += bfu_lo(uu.y); acc[3] += bfu_hi(uu.y);
                acc[4] += bfu_lo(uu.z); acc[5] += bfu_hi(uu.z);
                acc[6] += bfu_lo(uu.w); acc[7] += bfu_hi(uu.w);
            }
            float* gr = gl + ln * STR + q * 8;
#pragma unroll
            for (int j = 0; j < 8; ++j) gr[j] = acc[j];
        }
    }
    __syncthreads();
    // phase B: matmul from LDS
    for (int task = t; task < NPB * QO; task += 256) {
        int ln2 = task / QO, qq = task % QO;
        int n2 = n0 + ln2;
        if (n2 >= N) continue;
        float di = dl[ln2];
        const float* row = gl + ln2 * STR;
        float4 acc = make_float4(0.f, 0.f, 0.f, 0.f);
#pragma unroll
        for (int k = 0; k < FIN; ++k) {
            float rk = row[k];
            float4 wk = *(const float4*)(wl + k * FOUT + 4 * qq);
            acc.x = fmaf(rk, wk.x, acc.x);
            acc.y = fmaf(rk, wk.y, acc.y);
            acc.z = fmaf(rk, wk.z, acc.z);
            acc.w = fmaf(rk, wk.w, acc.w);
        }
        float4 bq = *(const float4*)(bl + 4 * qq);
        float4 v;
        v.x = fmaxf(di * acc.x + bq.x, 0.f);
        v.y = fmaxf(di * acc.y + bq.y, 0.f);
        v.z = fmaxf(di * acc.z + bq.z, 0.f);
        v.w = fmaxf(di * acc.w + bq.w, 0.f);
        if (PRESCALE_OUT) { v.x *= di; v.y *= di; v.z *= di; v.w *= di; }
        uint2 o;
        o.x = pack2(v.x, v.y);
        o.y = pack2(v.z, v.w);
        outb[(size_t)n2 * QO + qq] = o;
    }
}

// ---------------- pool + head (atomic-free, bf16 input) ----------------

__global__ void bounds_kernel(const int* __restrict__ batch, int* __restrict__ start,
                              int N, int G) {
    int g = blockIdx.x * blockDim.x + threadIdx.x;
    if (g > G) return;
    if (g == G) { start[G] = N; return; }
    int lo = 0, hi = N;
    while (lo < hi) {
        int mid = (lo + hi) >> 1;
        if (batch[mid] < g) lo = mid + 1; else hi = mid;
    }
    start[g] = lo;
}

__global__ void pool_head_kernel(const unsigned int* __restrict__ h, const int* __restrict__ start,
                                 const float* __restrict__ Wfc, const float* __restrict__ bfc,
                                 float* __restrict__ out) {
    __shared__ float part[8][64];
    int g = blockIdx.x;
    int t = threadIdx.x;          // 256
    int u = t & 31, w = t >> 5;
    int s = start[g], e = start[g + 1];
    float a0 = 0.f, a1 = 0.f;
    for (int n = s + w; n < e; n += 8) {
        unsigned int word = h[(size_t)n * 32 + u];
        a0 += bfu_lo(word);
        a1 += bfu_hi(word);
    }
    part[w][2 * u]     = a0;
    part[w][2 * u + 1] = a1;
    __syncthreads();
    if (t < 64) {
        float p = 0.f;
#pragma unroll
        for (int w2 = 0; w2 < 8; ++w2) p += part[w2][t];
        p /= fmaxf((float)(e - s), 1.0f);
        float l0 = p * Wfc[t * 2 + 0];
        float l1 = p * Wfc[t * 2 + 1];
#pragma unroll
        for (int off = 32; off; off >>= 1) {
            l0 += __shfl_down(l0, off);
            l1 += __shfl_down(l1, off);
        }
        if (t == 0) {
            l0 += bfc[0]; l1 += bfc[1];
            float m   = fmaxf(l0, l1);
            float lse = m + logf(expf(l0 - m) + expf(l1 - m));
            out[g * 2 + 0] = l0 - lse;
            out[g * 2 + 1] = l1 - lse;
        }
    }
}

// ---------------- driver ----------------

extern "C" void kernel_launch(void* const* d_in, const int* in_sizes, int n_in,
                              void* d_out, int out_size, void* d_ws, size_t ws_size,
                              hipStream_t stream) {
    const float* x     = (const float*)d_in[0];
    const int*   src   = (const int*)d_in[1];
    const int*   dst   = (const int*)d_in[2];
    const int*   batch = (const int*)d_in[3];
    const float* W1    = (const float*)d_in[4];
    const float* b1    = (const float*)d_in[5];
    const float* W2    = (const float*)d_in[6];
    const float* b2    = (const float*)d_in[7];
    const float* W3    = (const float*)d_in[8];
    const float* b3    = (const float*)d_in[9];
    const float* Wfc   = (const float*)d_in[10];
    const float* bfc   = (const float*)d_in[11];
    float* out = (float*)d_out;

    const int N = in_sizes[0] / 5;   // 100000  (must stay < 2^17 for packed pe)
    const int E = in_sizes[1];       // 1600000
    const int G = out_size / 2;      // 1024

    const int nChunks = (E + CH - 1) / CH;           // 391
    const int M       = NB * nChunks;                // ~100K
    const int Mpad    = (M + 3) & ~3;
    const int nGroups = (N + GSZ - 1) / GSZ;         // 196

    // workspace layout (4B units; all region sizes multiples of 4; N%4==0)
    int* row_ptr  = (int*)d_ws;                   // N+4 (uses N+1)
    int* col      = row_ptr + N + 4;              // E
    int* cnt      = col + E;                      // Mpad
    int* groupBeg = cnt + Mpad;                   // 260 (uses NB+1)
    int* bucketTot= groupBeg + 260;               // 256
    int* start    = bucketTot + 256;              // G+8 (uses G+1)
    float* dinv   = (float*)(start + G + 8);      // N
    int*   Xa     = (int*)(dinv + N);             // N*16 ints: Xs1[N,8] / Xs3[N,32] bf16
    int*   Xb     = Xa + (size_t)N * 16;          // N*8  ints: Xs2[N,16] bf16
    int*   H3b    = Xb + (size_t)N * 8;           // N*32 ints: out3[N,64] bf16
    int*   pe     = H3b;                          // E ints (aliases H3b; dead before layer 3)
    // total ~ 30 MB

    auto blocks = [](long n) { return (int)((n + BLK - 1) / BLK); };

    // ---- CSR build: exact counting sort; parallel separable scan ----
    hist1_kernel<<<nChunks, 256, 0, stream>>>(dst, cnt, E, nChunks);
    seg_scan_kernel<<<NB, 256, 0, stream>>>(cnt, bucketTot, nChunks);
    bucket_scan_kernel<<<1, 256, 0, stream>>>(bucketTot, groupBeg, E);
    scatter1_kernel<<<nChunks, 256, 0, stream>>>(src, dst, cnt, groupBeg, pe, E, nChunks);
    group_csr_kernel<<<nGroups, 256, 0, stream>>>(pe, groupBeg, col, row_ptr, dinv,
                                                  x, (uint4*)Xa, N, E);   // + fused prescale

    // ---- pool boundaries ----
    bounds_kernel<<<blocks(G + 1), BLK, 0, stream>>>(batch, start, N, G);

    // ---- layer 1: Xa[N,8] -> Xb[N,16]   (F=8: 256 nodes/block) ----
    fused_layer_kernel<8, 5, 16, 6144, true><<<(N + 255) / 256, 256, 0, stream>>>(
        row_ptr, col, (const uint4*)Xa, W1, b1, dinv, (uint2*)Xb, N);

    // ---- layer 2: Xb[N,16] -> Xa[N,32]  (F=16: 128 nodes/block) ----
    fused_layer_kernel<16, 16, 32, 4096, true><<<(N + 127) / 128, 256, 0, stream>>>(
        row_ptr, col, (const uint4*)Xb, W2, b2, dinv, (uint2*)Xa, N);

    // ---- layer 3: Xa[N,32] -> H3b[N,64] (F=32: 64 nodes/block) ----
    fused_layer_kernel<32, 32, 64, 2048, false><<<(N + 63) / 64, 256, 0, stream>>>(
        row_ptr, col, (const uint4*)Xa, W3, b3, dinv, (uint2*)H3b, N);

    // ---- mean pool + head (no atomics, bf16 input) ----
    pool_head_kernel<<<G, 256, 0, stream>>>((const unsigned int*)H3b, start, Wfc, bfc, out);
}